// Round 1
// baseline (8234.294 us; speedup 1.0000x reference)
//
#include <hip/hip_runtime.h>
#include <math.h>

#define PI_F 3.14159265358979323846f

// One conv stage: in = concat(in1[C1], x_group[4]) -> relu(conv KSxKS) -> out (optional)
// Also reduces each output channel plane to (s0, s1) DCT partial sums.
// Block: 256 threads, handles one (branch, image, 8 output channels), full 32x32 plane.
template<int KS, int C1, int COUT>
__global__ __launch_bounds__(256) void conv_stage(
    const float* __restrict__ in1,   // [nb][16][C1][1024] or unused
    const float* __restrict__ x,     // [16][16][1024]
    const float* __restrict__ wgt,   // [8][COUT][C1+4][KS*KS]
    const float* __restrict__ bias,  // [8][COUT]
    float* __restrict__ out,         // [nb][16][COUT][1024] or nullptr
    float* __restrict__ sums,        // [16][3584][2]
    int i_base, int fused_off)
{
    constexpr int PAD = KS / 2;
    constexpr int P   = 32 + 2 * PAD;
    constexpr int CIN = C1 + 4;
    constexpr int NCB = COUT / 8;
    __shared__ float lds[4 * P * P];

    const int t = threadIdx.x;
    const int cb    = blockIdx.x % NCB;
    const int rest  = blockIdx.x / NCB;
    const int b     = rest % 16;
    const int i_loc = rest / 16;
    const int i = i_base + i_loc;
    const int g = i >> 1;

    const int w0i = t & 31;
    const int h0  = t >> 5;          // 0..7; thread covers rows h0, h0+8, h0+16, h0+24

    float acc[4][8];
    #pragma unroll
    for (int pj = 0; pj < 4; ++pj)
        #pragma unroll
        for (int co = 0; co < 8; ++co) acc[pj][co] = 0.f;

    const size_t ib  = (size_t)(i_loc * 16 + b);
    const int co_g = cb * 8;

    for (int c0 = 0; c0 < CIN; c0 += 4) {
        __syncthreads();
        // stage 4 input channels (zero-padded) into LDS
        for (int e = t; e < 4 * P * P; e += 256) {
            int c  = e / (P * P);
            int r  = e - c * (P * P);
            int ph = r / P;
            int pw = r - ph * P;
            int hh = ph - PAD, ww = pw - PAD;
            float v = 0.f;
            if (hh >= 0 && hh < 32 && ww >= 0 && ww < 32) {
                int cin = c0 + c;
                if (C1 > 0 && cin < C1)
                    v = in1[(ib * C1 + cin) * 1024 + hh * 32 + ww];
                else
                    v = x[((size_t)b * 16 + g * 4 + (cin - C1)) * 1024 + hh * 32 + ww];
            }
            lds[e] = v;
        }
        __syncthreads();

        for (int c = 0; c < 4; ++c) {
            const int cin = c0 + c;  // block-uniform
            const float* wp = wgt + (((size_t)i * COUT + co_g) * CIN + cin) * (KS * KS);
            #pragma unroll
            for (int kh = 0; kh < KS; ++kh) {
                #pragma unroll
                for (int kw = 0; kw < KS; ++kw) {
                    float wr[8];
                    #pragma unroll
                    for (int co = 0; co < 8; ++co)
                        wr[co] = wp[(size_t)co * CIN * KS * KS + kh * KS + kw]; // uniform -> s_load
                    #pragma unroll
                    for (int pj = 0; pj < 4; ++pj) {
                        float v = lds[c * P * P + (h0 + 8 * pj + kh) * P + (w0i + kw)];
                        #pragma unroll
                        for (int co = 0; co < 8; ++co)
                            acc[pj][co] = fmaf(v, wr[co], acc[pj][co]);
                    }
                }
            }
        }
    }

    // epilogue: bias + relu + (optional store) + DCT partial reduction
    const float cw = cosf(PI_F * (w0i + 0.5f) / 32.0f);
    float s0[8], s1[8];
    #pragma unroll
    for (int co = 0; co < 8; ++co) { s0[co] = 0.f; s1[co] = 0.f; }
    #pragma unroll
    for (int co = 0; co < 8; ++co) {
        float bia = bias[i * COUT + co_g + co];
        #pragma unroll
        for (int pj = 0; pj < 4; ++pj) {
            float v = fmaxf(acc[pj][co] + bia, 0.f);
            if (out) out[(ib * COUT + co_g + co) * 1024 + t + 256 * pj] = v;
            s0[co] += v;
            s1[co] += v * cw;
        }
    }

    __syncthreads();
    float* red = lds;  // reuse LDS: [4 waves][8 co][2]
    const int lane = t & 63, wv = t >> 6;
    #pragma unroll
    for (int co = 0; co < 8; ++co) {
        float r0 = s0[co], r1 = s1[co];
        for (int m = 1; m < 64; m <<= 1) { r0 += __shfl_xor(r0, m); r1 += __shfl_xor(r1, m); }
        if (lane == 0) { red[(wv * 8 + co) * 2 + 0] = r0; red[(wv * 8 + co) * 2 + 1] = r1; }
    }
    __syncthreads();
    if (t < 16) {
        int co = t >> 1, k = t & 1;
        float v = red[(0 * 8 + co) * 2 + k] + red[(1 * 8 + co) * 2 + k]
                + red[(2 * 8 + co) * 2 + k] + red[(3 * 8 + co) * 2 + k];
        int ch = i * 448 + fused_off + co_g + co;
        sums[((size_t)b * 3584 + ch) * 2 + k] = v;
    }
}

// Head: LayerNorm over 7168 dct features + two small GEMVs per image.
__global__ __launch_bounds__(256) void head_kernel(
    const float* __restrict__ sums,   // [16][7168]  (= dct features)
    const float* __restrict__ Wg, const float* __restrict__ bg,
    const float* __restrict__ gamma, const float* __restrict__ beta,
    const float* __restrict__ Wd, const float* __restrict__ bd,
    float* __restrict__ out)          // [960 gap][960 dct]
{
    __shared__ float nrm[7168];
    __shared__ float gf[3584];
    __shared__ float red[8];
    const int b = blockIdx.x;
    const int t = threadIdx.x, lane = t & 63, wv = t >> 6;
    const float* S = sums + (size_t)b * 7168;

    float ls = 0.f, lq = 0.f;
    for (int f = t; f < 7168; f += 256) { float v = S[f]; ls += v; lq += v * v; }
    for (int m = 1; m < 64; m <<= 1) { ls += __shfl_xor(ls, m); lq += __shfl_xor(lq, m); }
    if (lane == 0) { red[wv] = ls; red[4 + wv] = lq; }
    __syncthreads();
    float ts = red[0] + red[1] + red[2] + red[3];
    float tq = red[4] + red[5] + red[6] + red[7];
    float mu  = ts * (1.f / 7168.f);
    float var = tq * (1.f / 7168.f) - mu * mu;
    float inv = rsqrtf(var + 1e-5f);

    for (int f = t; f < 7168; f += 256) nrm[f] = (S[f] - mu) * inv * gamma[f] + beta[f];
    for (int ch = t; ch < 3584; ch += 256) gf[ch] = S[2 * ch];
    __syncthreads();

    // 4 waves x 15 outputs each = 60 classes
    for (int j = 0; j < 15; ++j) {
        int n = wv * 15 + j;
        float accg = 0.f, accd = 0.f;
        for (int ch = lane; ch < 3584; ch += 64) accg += gf[ch] * Wg[(size_t)n * 3584 + ch];
        for (int f = lane; f < 7168; f += 64)    accd += nrm[f] * Wd[(size_t)n * 7168 + f];
        for (int m = 1; m < 64; m <<= 1) { accg += __shfl_xor(accg, m); accd += __shfl_xor(accd, m); }
        if (lane == 0) {
            out[b * 60 + n]       = accg * (1.f / 1024.f) + bg[n];
            out[960 + b * 60 + n] = accd + bd[n];
        }
    }
}

extern "C" void kernel_launch(void* const* d_in, const int* in_sizes, int n_in,
                              void* d_out, int out_size, void* d_ws, size_t ws_size,
                              hipStream_t stream)
{
    const float* x     = (const float*)d_in[0];
    const float* w3    = (const float*)d_in[1];
    const float* b3    = (const float*)d_in[2];
    const float* w5    = (const float*)d_in[3];
    const float* b5    = (const float*)d_in[4];
    const float* w7    = (const float*)d_in[5];
    const float* b7    = (const float*)d_in[6];
    const float* Wg    = (const float*)d_in[7];
    const float* bg    = (const float*)d_in[8];
    const float* gamma = (const float*)d_in[9];
    const float* beta  = (const float*)d_in[10];
    const float* Wd    = (const float*)d_in[11];
    const float* bd    = (const float*)d_in[12];
    float* out = (float*)d_out;

    const size_t SUMS = (size_t)16 * 3584 * 2;      // 114688 floats
    const size_t A1   = (size_t)16 * 64 * 1024;     // per-branch a buffer
    const size_t B1   = (size_t)16 * 128 * 1024;    // per-branch b buffer

    int nb = 8;
    while (nb > 1 && (SUMS + (size_t)nb * (A1 + B1)) * 4 > ws_size) nb >>= 1;

    float* sums = (float*)d_ws;
    float* aBuf = sums + SUMS;
    float* bBuf = aBuf + (size_t)nb * A1;

    for (int ib = 0; ib < 8; ib += nb) {
        conv_stage<3, 0,   64 ><<<dim3(nb * 16 * 8),  dim3(256), 0, stream>>>(nullptr, x, w3, b3, aBuf,    sums, ib, 0);
        conv_stage<5, 64,  128><<<dim3(nb * 16 * 16), dim3(256), 0, stream>>>(aBuf,    x, w5, b5, bBuf,    sums, ib, 64);
        conv_stage<7, 128, 256><<<dim3(nb * 16 * 32), dim3(256), 0, stream>>>(bBuf,    x, w7, b7, nullptr, sums, ib, 192);
    }
    head_kernel<<<dim3(16), dim3(256), 0, stream>>>(sums, Wg, bg, gamma, beta, Wd, bd, out);
}

// Round 2
// 1420.363 us; speedup vs baseline: 5.7973x; 5.7973x over previous
//
#include <hip/hip_runtime.h>
#include <math.h>

#define PI_F 3.14159265358979323846f

typedef short bf16x8 __attribute__((ext_vector_type(8)));
typedef float f32x4  __attribute__((ext_vector_type(4)));

__device__ __forceinline__ short f2bf(float f) {
    union { float f; unsigned u; } v; v.f = f;
    unsigned r = v.u + 0x7fffu + ((v.u >> 16) & 1u);
    return (short)(r >> 16);
}

// ---------------- prep kernels ----------------

// s1in: [b][g][1024][32] bf16, ch 0..3 = x group, 4..31 = 0
__global__ __launch_bounds__(256) void prep_s1in(const float* __restrict__ x, short* __restrict__ dst) {
    int idx = blockIdx.x * 256 + threadIdx.x;          // chunk index (8 ch per chunk)
    if (idx >= 16 * 4 * 1024 * 4) return;
    int kc = idx & 3;
    int px = (idx >> 2) & 1023;
    int g  = (idx >> 12) & 3;
    int b  = idx >> 14;
    short v8[8];
    #pragma unroll
    for (int j = 0; j < 8; ++j) {
        int ch = kc * 8 + j;
        float f = (ch < 4) ? x[((b * 16 + g * 4 + ch) << 10) + px] : 0.f;
        v8[j] = f2bf(f);
    }
    *(int4*)(dst + (size_t)idx * 8) = *(const int4*)v8;
}

// write x-group (4 ch) + 4 zeros at channel CH0 of a [pair][1024][CHS] bf16 buffer
__global__ __launch_bounds__(256) void prep_sx(const float* __restrict__ x, short* __restrict__ dst,
                                               int CHS, int CH0) {
    int idx = blockIdx.x * 256 + threadIdx.x;          // (pair, px)
    if (idx >= 128 * 1024) return;
    int px = idx & 1023, pair = idx >> 10;
    int i = pair >> 4, b = pair & 15, g = i >> 1;
    short v8[8];
    #pragma unroll
    for (int j = 0; j < 8; ++j) {
        float f = (j < 4) ? x[((b * 16 + g * 4 + j) << 10) + px] : 0.f;
        v8[j] = f2bf(f);
    }
    *(int4*)(dst + (size_t)idx * CHS + CH0) = *(const int4*)v8;
}

// weights [8][COUT][CINR][NT] fp32 -> [8][NT][COUT][CHS] bf16 (ch >= CINR zero)
__global__ __launch_bounds__(256) void wprep(const float* __restrict__ w, short* __restrict__ Bw,
                                             int NT, int COUT, int CINR, int CHS, int total) {
    int idx = blockIdx.x * 256 + threadIdx.x;
    if (idx >= total) return;
    int nc8 = CHS >> 3;
    int kc = idx % nc8; int r  = idx / nc8;
    int n  = r % COUT;  int r2 = r / COUT;
    int tap = r2 % NT;  int br = r2 / NT;
    short v8[8];
    #pragma unroll
    for (int j = 0; j < 8; ++j) {
        int ch = kc * 8 + j;
        float f = (ch < CINR) ? w[((br * COUT + n) * CINR + ch) * NT + tap] : 0.f;
        v8[j] = f2bf(f);
    }
    *(int4*)(Bw + (size_t)idx * 8) = *(const int4*)v8;
}

// ---------------- MFMA conv stage ----------------
// block: 512 thr = 8 waves (4M x 2N). M=256 spatial rows (8 image rows), N=COUT.
// A tile in LDS: [TR][TC][32ch] bf16, chunk-XOR swizzle by (pixel&3).
// B panels double-buffered: [COUT][32ch], chunk-XOR swizzle by (n&3).
template<int KS, int NKS, int COUT, int CHS_IN, int CHS_OUT, int FOFF, bool S1SRC>
__global__ __launch_bounds__(512, 2) void conv_mfma(
    const short* __restrict__ sIn,
    short* __restrict__ sOut,
    const short* __restrict__ Bw,      // [8][NT][COUT][CHS_IN] bf16
    const float* __restrict__ bias,    // [8][COUT]
    float* __restrict__ sums)          // [16][3584][2] fp32
{
    constexpr int PAD = KS / 2;
    constexpr int TR  = 8 + KS - 1;
    constexpr int TC  = 32 + KS - 1;
    constexpr int NT  = KS * KS;
    constexpr int NFN = COUT / 32;     // B frags per wave (Nw = COUT/2)
    constexpr int ACH = TR * TC;       // pixels in A tile
    constexpr int NCB = COUT * 4;      // 16B chunks per B panel

    __shared__ int4 AtileV[(ACH * 32) / 8];
    __shared__ int4 BtileV[(2 * COUT * 32) / 8];
    short* Atile = (short*)AtileV;
    short* Btile = (short*)BtileV;

    const int t    = threadIdx.x;
    const int lane = t & 63, w = t >> 6;
    const int wm = w >> 1, wn = w & 1;
    const int lm = lane & 15, kb = lane >> 4;

    const int bid = blockIdx.x;
    const int i  = bid & 7;            // branch (-> XCD via %8)
    const int b  = (bid >> 3) & 15;    // image
    const int mt = bid >> 7;           // m-tile
    const int r0 = mt * 8;             // first output image row

    // A-frag per-lane pixel bases (tap adds kh*TC + kw)
    int pb[4];
    #pragma unroll
    for (int fm = 0; fm < 4; ++fm) {
        int imgrow = wm * 2 + (fm >> 1);
        int col    = (fm & 1) * 16 + lm;
        pb[fm] = imgrow * TC + col;
    }
    // B-frag per-lane offsets (shorts within one buffer)
    int boff[NFN];
    #pragma unroll
    for (int fn = 0; fn < NFN; ++fn) {
        int n = wn * (COUT / 2) + fn * 16 + lm;
        boff[fn] = n * 32 + ((kb ^ (n & 3)) << 3);
    }

    f32x4 acc[4][NFN];
    #pragma unroll
    for (int fm = 0; fm < 4; ++fm)
        #pragma unroll
        for (int fn = 0; fn < NFN; ++fn)
            acc[fm][fn] = (f32x4){0.f, 0.f, 0.f, 0.f};

    const int pairPx = (i * 16 + b) << 10;
    const int srcPx  = S1SRC ? ((b * 4 + (i >> 1)) << 10) : pairPx;

    auto stageA = [&](int ks) {
        for (int e = t; e < ACH * 4; e += 512) {
            int pix = e >> 2, kc = e & 3;
            int tr = pix / TC, c = pix - tr * TC;
            int R = r0 - PAD + tr, C = c - PAD;
            int ch = ks * 32 + kc * 8;
            int4 val = {0, 0, 0, 0};
            if (R >= 0 && R < 32 && C >= 0 && C < 32 && ch < CHS_IN)
                val = *(const int4*)(sIn + (size_t)(srcPx + R * 32 + C) * CHS_IN + ch);
            *(int4*)(Atile + pix * 32 + ((kc ^ (pix & 3)) << 3)) = val;
        }
    };

    // initial: B(ks=0, tap=0) into buf0 + A(ks=0)
    for (int c = t; c < NCB; c += 512) {
        int n = c >> 2, kc = c & 3;
        int ch = kc * 8;
        int4 v = {0, 0, 0, 0};
        if (ch < CHS_IN) v = *(const int4*)(Bw + (size_t)((i * NT + 0) * COUT + n) * CHS_IN + ch);
        *(int4*)(Btile + n * 32 + ((kc ^ (n & 3)) << 3)) = v;
    }
    stageA(0);
    __syncthreads();

    int buf = 0;
    for (int ks = 0; ks < NKS; ++ks) {
        for (int tap = 0; tap < NT; ++tap) {
            const bool lastTap = (tap == NT - 1);
            const bool hasNext = !(lastTap && ks == NKS - 1);
            const int nks  = lastTap ? ks + 1 : ks;
            const int ntap = lastTap ? 0 : tap + 1;

            // issue next-B global loads (latency hidden under MFMAs)
            int4 br0 = {0, 0, 0, 0}, br1 = {0, 0, 0, 0};
            if (hasNext) {
                {
                    int c = t;
                    if (c < NCB) {
                        int n = c >> 2, kc = c & 3;
                        int ch = nks * 32 + kc * 8;
                        if (ch < CHS_IN)
                            br0 = *(const int4*)(Bw + (size_t)((i * NT + ntap) * COUT + n) * CHS_IN + ch);
                    }
                }
                if constexpr (NCB > 512) {
                    int c2 = t + 512;
                    int n = c2 >> 2, kc = c2 & 3;
                    int ch = nks * 32 + kc * 8;
                    if (ch < CHS_IN)
                        br1 = *(const int4*)(Bw + (size_t)((i * NT + ntap) * COUT + n) * CHS_IN + ch);
            }
            }

            // compute this tap
            const int kh = tap / KS, kw = tap - kh * KS;
            const int toff = kh * TC + kw;
            const short* Bt = Btile + buf * (COUT * 32);

            bf16x8 af[4];
            #pragma unroll
            for (int fm = 0; fm < 4; ++fm) {
                int p = pb[fm] + toff;
                af[fm] = *(const bf16x8*)(Atile + p * 32 + ((kb ^ (p & 3)) << 3));
            }
            bf16x8 bfr[NFN];
            #pragma unroll
            for (int fn = 0; fn < NFN; ++fn)
                bfr[fn] = *(const bf16x8*)(Bt + boff[fn]);
            #pragma unroll
            for (int fm = 0; fm < 4; ++fm)
                #pragma unroll
                for (int fn = 0; fn < NFN; ++fn)
                    acc[fm][fn] = __builtin_amdgcn_mfma_f32_16x16x32_bf16(af[fm], bfr[fn], acc[fm][fn], 0, 0, 0);

            // write next B into the other buffer
            if (hasNext) {
                short* Bn = Btile + (buf ^ 1) * (COUT * 32);
                {
                    int c = t;
                    if (c < NCB) {
                        int n = c >> 2, kc = c & 3;
                        *(int4*)(Bn + n * 32 + ((kc ^ (n & 3)) << 3)) = br0;
                    }
                }
                if constexpr (NCB > 512) {
                    int c2 = t + 512;
                    int n = c2 >> 2, kc = c2 & 3;
                    *(int4*)(Bn + n * 32 + ((kc ^ (n & 3)) << 3)) = br1;
                }
            }
            __syncthreads();
            if (lastTap && ks + 1 < NKS) {
                stageA(ks + 1);
                __syncthreads();
            }
            buf ^= 1;
        }
    }

    // ---------------- epilogue: bias + relu + store + DCT reduction ----------------
    float cwv[2][4];
    #pragma unroll
    for (int par = 0; par < 2; ++par)
        #pragma unroll
        for (int r = 0; r < 4; ++r)
            cwv[par][r] = cosf(PI_F * (par * 16 + kb * 4 + r + 0.5f) / 32.f);

    #pragma unroll
    for (int fn = 0; fn < NFN; ++fn) {
        int n = wn * (COUT / 2) + fn * 16 + lm;
        float bv = bias[i * COUT + n];
        float s0 = 0.f, s1 = 0.f;
        #pragma unroll
        for (int fm = 0; fm < 4; ++fm) {
            int imgrow = wm * 2 + (fm >> 1);
            int par = fm & 1;
            #pragma unroll
            for (int r = 0; r < 4; ++r) {
                float v = fmaxf(acc[fm][fn][r] + bv, 0.f);
                if constexpr (CHS_OUT > 0) {
                    int col = par * 16 + kb * 4 + r;
                    int R = r0 + imgrow;
                    sOut[(size_t)(pairPx + R * 32 + col) * CHS_OUT + n] = f2bf(v);
                }
                s0 += v;
                s1 += v * cwv[par][r];
            }
        }
        s0 += __shfl_xor(s0, 16); s1 += __shfl_xor(s1, 16);
        s0 += __shfl_xor(s0, 32); s1 += __shfl_xor(s1, 32);
        if (kb == 0) {
            int ch = i * 448 + FOFF + n;
            atomicAdd(&sums[((size_t)b * 3584 + ch) * 2 + 0], s0);
            atomicAdd(&sums[((size_t)b * 3584 + ch) * 2 + 1], s1);
        }
    }
}

// ---------------- head: LayerNorm + two GEMVs per image ----------------
__global__ __launch_bounds__(256) void head_kernel(
    const float* __restrict__ sums,   // [16][7168]
    const float* __restrict__ Wg, const float* __restrict__ bg,
    const float* __restrict__ gamma, const float* __restrict__ beta,
    const float* __restrict__ Wd, const float* __restrict__ bd,
    float* __restrict__ out)          // [960 gap][960 dct]
{
    __shared__ float nrm[7168];
    __shared__ float gf[3584];
    __shared__ float red[8];
    const int b = blockIdx.x;
    const int t = threadIdx.x, lane = t & 63, wv = t >> 6;
    const float* S = sums + (size_t)b * 7168;

    float ls = 0.f, lq = 0.f;
    for (int f = t; f < 7168; f += 256) { float v = S[f]; ls += v; lq += v * v; }
    for (int m = 1; m < 64; m <<= 1) { ls += __shfl_xor(ls, m); lq += __shfl_xor(lq, m); }
    if (lane == 0) { red[wv] = ls; red[4 + wv] = lq; }
    __syncthreads();
    float ts = red[0] + red[1] + red[2] + red[3];
    float tq = red[4] + red[5] + red[6] + red[7];
    float mu  = ts * (1.f / 7168.f);
    float var = tq * (1.f / 7168.f) - mu * mu;
    float inv = rsqrtf(var + 1e-5f);

    for (int f = t; f < 7168; f += 256) nrm[f] = (S[f] - mu) * inv * gamma[f] + beta[f];
    for (int ch = t; ch < 3584; ch += 256) gf[ch] = S[2 * ch];
    __syncthreads();

    for (int j = 0; j < 15; ++j) {
        int n = wv * 15 + j;
        float accg = 0.f, accd = 0.f;
        for (int ch = lane; ch < 3584; ch += 64) accg += gf[ch] * Wg[(size_t)n * 3584 + ch];
        for (int f = lane; f < 7168; f += 64)    accd += nrm[f] * Wd[(size_t)n * 7168 + f];
        for (int m = 1; m < 64; m <<= 1) { accg += __shfl_xor(accg, m); accd += __shfl_xor(accd, m); }
        if (lane == 0) {
            out[b * 60 + n]       = accg * (1.f / 1024.f) + bg[n];
            out[960 + b * 60 + n] = accd + bd[n];
        }
    }
}

extern "C" void kernel_launch(void* const* d_in, const int* in_sizes, int n_in,
                              void* d_out, int out_size, void* d_ws, size_t ws_size,
                              hipStream_t stream)
{
    const float* x     = (const float*)d_in[0];
    const float* w3    = (const float*)d_in[1];
    const float* b3    = (const float*)d_in[2];
    const float* w5    = (const float*)d_in[3];
    const float* b5    = (const float*)d_in[4];
    const float* w7    = (const float*)d_in[5];
    const float* b7    = (const float*)d_in[6];
    const float* Wg    = (const float*)d_in[7];
    const float* bg    = (const float*)d_in[8];
    const float* gamma = (const float*)d_in[9];
    const float* beta  = (const float*)d_in[10];
    const float* Wd    = (const float*)d_in[11];
    const float* bd    = (const float*)d_in[12];
    float* out = (float*)d_out;

    // workspace layout (bytes)
    char* p = (char*)d_ws;
    float* sums = (float*)p;              p += 458752;      // 16*3584*2 f32
    short* s1in = (short*)p;              p += 4194304;     // [16][4][1024][32] bf16
    short* s2in = (short*)p;              p += 18874368;    // [128][1024][72]  bf16
    short* s3in = (short*)p;              p += 35651584;    // [128][1024][136] bf16
    short* Bw3  = (short*)p;              p += 294912;      // [8][9][64][32]
    short* Bw5  = (short*)p;              p += 3686400;     // [8][25][128][72]
    short* Bw7  = (short*)p;              p += 27262976;    // [8][49][256][136]

    hipMemsetAsync(sums, 0, 458752, stream);
    prep_s1in<<<dim3(1024), dim3(256), 0, stream>>>(x, s1in);
    prep_sx<<<dim3(512), dim3(256), 0, stream>>>(x, s2in, 72, 64);
    prep_sx<<<dim3(512), dim3(256), 0, stream>>>(x, s3in, 136, 128);
    wprep<<<dim3((18432 + 255) / 256), dim3(256), 0, stream>>>(w3, Bw3, 9, 64, 4, 32, 18432);
    wprep<<<dim3((230400 + 255) / 256), dim3(256), 0, stream>>>(w5, Bw5, 25, 128, 68, 72, 230400);
    wprep<<<dim3((1705984 + 255) / 256), dim3(256), 0, stream>>>(w7, Bw7, 49, 256, 132, 136, 1705984);

    conv_mfma<3, 1, 64, 32, 72, 0, true><<<dim3(512), dim3(512), 0, stream>>>(s1in, s2in, Bw3, b3, sums);
    conv_mfma<5, 3, 128, 72, 136, 64, false><<<dim3(512), dim3(512), 0, stream>>>(s2in, s3in, Bw5, b5, sums);
    conv_mfma<7, 5, 256, 136, 0, 192, false><<<dim3(512), dim3(512), 0, stream>>>(s3in, nullptr, Bw7, b7, sums);

    head_kernel<<<dim3(16), dim3(256), 0, stream>>>(sums, Wg, bg, gamma, beta, Wd, bd, out);
}

// Round 3
// 721.426 us; speedup vs baseline: 11.4139x; 1.9688x over previous
//
#include <hip/hip_runtime.h>
#include <math.h>

#define PI_F 3.14159265358979323846f

typedef short bf16x8 __attribute__((ext_vector_type(8)));
typedef float f32x4  __attribute__((ext_vector_type(4)));

__device__ __forceinline__ short f2bf(float f) {
    union { float f; unsigned u; } v; v.f = f;
    unsigned r = v.u + 0x7fffu + ((v.u >> 16) & 1u);
    return (short)(r >> 16);
}

// ---------------- prep kernels ----------------

// s1in: [b][g][1024][32] bf16, ch 0..3 = x group, 4..31 = 0
__global__ __launch_bounds__(256) void prep_s1in(const float* __restrict__ x, short* __restrict__ dst) {
    int idx = blockIdx.x * 256 + threadIdx.x;          // chunk index (8 ch per chunk)
    if (idx >= 16 * 4 * 1024 * 4) return;
    int kc = idx & 3;
    int px = (idx >> 2) & 1023;
    int g  = (idx >> 12) & 3;
    int b  = idx >> 14;
    short v8[8];
    #pragma unroll
    for (int j = 0; j < 8; ++j) {
        int ch = kc * 8 + j;
        float f = (ch < 4) ? x[((b * 16 + g * 4 + ch) << 10) + px] : 0.f;
        v8[j] = f2bf(f);
    }
    *(int4*)(dst + (size_t)idx * 8) = *(const int4*)v8;
}

// write x-group (4 ch) + 4 zeros at channel CH0 of a [pair][1024][CHS] bf16 buffer
__global__ __launch_bounds__(256) void prep_sx(const float* __restrict__ x, short* __restrict__ dst,
                                               int CHS, int CH0) {
    int idx = blockIdx.x * 256 + threadIdx.x;          // (pair, px)
    if (idx >= 128 * 1024) return;
    int px = idx & 1023, pair = idx >> 10;
    int i = pair >> 4, b = pair & 15, g = i >> 1;
    short v8[8];
    #pragma unroll
    for (int j = 0; j < 8; ++j) {
        float f = (j < 4) ? x[((b * 16 + g * 4 + j) << 10) + px] : 0.f;
        v8[j] = f2bf(f);
    }
    *(int4*)(dst + (size_t)idx * CHS + CH0) = *(const int4*)v8;
}

// weights [8][COUT][CINR][NT] fp32 -> [8][NT][COUT][CHS] bf16 (ch >= CINR zero)
__global__ __launch_bounds__(256) void wprep(const float* __restrict__ w, short* __restrict__ Bw,
                                             int NT, int COUT, int CINR, int CHS, int total) {
    int idx = blockIdx.x * 256 + threadIdx.x;
    if (idx >= total) return;
    int nc8 = CHS >> 3;
    int kc = idx % nc8; int r  = idx / nc8;
    int n  = r % COUT;  int r2 = r / COUT;
    int tap = r2 % NT;  int br = r2 / NT;
    short v8[8];
    #pragma unroll
    for (int j = 0; j < 8; ++j) {
        int ch = kc * 8 + j;
        float f = (ch < CINR) ? w[((br * COUT + n) * CINR + ch) * NT + tap] : 0.f;
        v8[j] = f2bf(f);
    }
    *(int4*)(Bw + (size_t)idx * 8) = *(const int4*)v8;
}

// ---------------- MFMA conv stage ----------------
// block: 512 thr = 8 waves (4M x 2N). M=256 spatial rows (8 image rows), N=COUT.
// A tile in LDS: [TR][TC][32ch] bf16, chunk-XOR swizzle by (pixel&3).
// B panels double-buffered: [COUT][32ch], chunk-XOR swizzle by (n&3).
template<int KS, int NKS, int COUT, int CHS_IN, int CHS_OUT, int FOFF, bool S1SRC>
__global__ __launch_bounds__(512, 2) void conv_mfma(
    const short* __restrict__ sIn,
    short* __restrict__ sOut,
    const short* __restrict__ Bw,      // [8][NT][COUT][CHS_IN] bf16
    const float* __restrict__ bias,    // [8][COUT]
    float* __restrict__ sums)          // [16][3584][2] fp32
{
    constexpr int PAD = KS / 2;
    constexpr int TR  = 8 + KS - 1;
    constexpr int TC  = 32 + KS - 1;
    constexpr int NT  = KS * KS;
    constexpr int NFN = COUT / 32;     // B frags per wave (Nw = COUT/2)
    constexpr int ACH = TR * TC;       // pixels in A tile
    constexpr int NCB = COUT * 4;      // 16B chunks per B panel

    __shared__ int4 AtileV[(ACH * 32) / 8];
    __shared__ int4 BtileV[(2 * COUT * 32) / 8];
    short* Atile = (short*)AtileV;
    short* Btile = (short*)BtileV;

    const int t    = threadIdx.x;
    const int lane = t & 63, w = t >> 6;
    const int wm = w >> 1, wn = w & 1;
    const int lm = lane & 15, kb = lane >> 4;

    const int bid = blockIdx.x;
    const int i  = bid & 7;            // branch (-> XCD via %8)
    const int b  = (bid >> 3) & 15;    // image
    const int mt = bid >> 7;           // m-tile
    const int r0 = mt * 8;             // first output image row

    // A-frag per-lane pixel bases (tap adds kh*TC + kw)
    int pb[4];
    #pragma unroll
    for (int fm = 0; fm < 4; ++fm) {
        int imgrow = wm * 2 + (fm >> 1);
        int col    = (fm & 1) * 16 + lm;
        pb[fm] = imgrow * TC + col;
    }
    // B-frag per-lane offsets (shorts within one buffer)
    int boff[NFN];
    #pragma unroll
    for (int fn = 0; fn < NFN; ++fn) {
        int n = wn * (COUT / 2) + fn * 16 + lm;
        boff[fn] = n * 32 + ((kb ^ (n & 3)) << 3);
    }

    f32x4 acc[4][NFN];
    #pragma unroll
    for (int fm = 0; fm < 4; ++fm)
        #pragma unroll
        for (int fn = 0; fn < NFN; ++fn)
            acc[fm][fn] = (f32x4){0.f, 0.f, 0.f, 0.f};

    const int pairPx = (i * 16 + b) << 10;
    const int srcPx  = S1SRC ? ((b * 4 + (i >> 1)) << 10) : pairPx;

    auto stageA = [&](int ks) {
        for (int e = t; e < ACH * 4; e += 512) {
            int pix = e >> 2, kc = e & 3;
            int tr = pix / TC, c = pix - tr * TC;
            int R = r0 - PAD + tr, C = c - PAD;
            int ch = ks * 32 + kc * 8;
            int4 val = {0, 0, 0, 0};
            if (R >= 0 && R < 32 && C >= 0 && C < 32 && ch < CHS_IN)
                val = *(const int4*)(sIn + (size_t)(srcPx + R * 32 + C) * CHS_IN + ch);
            *(int4*)(Atile + pix * 32 + ((kc ^ (pix & 3)) << 3)) = val;
        }
    };

    // initial: B(ks=0, tap=0) into buf0 + A(ks=0)
    for (int c = t; c < NCB; c += 512) {
        int n = c >> 2, kc = c & 3;
        int ch = kc * 8;
        int4 v = {0, 0, 0, 0};
        if (ch < CHS_IN) v = *(const int4*)(Bw + (size_t)((i * NT + 0) * COUT + n) * CHS_IN + ch);
        *(int4*)(Btile + n * 32 + ((kc ^ (n & 3)) << 3)) = v;
    }
    stageA(0);
    __syncthreads();

    int buf = 0;
    for (int ks = 0; ks < NKS; ++ks) {
        for (int tap = 0; tap < NT; ++tap) {
            const bool lastTap = (tap == NT - 1);
            const bool hasNext = !(lastTap && ks == NKS - 1);
            const int nks  = lastTap ? ks + 1 : ks;
            const int ntap = lastTap ? 0 : tap + 1;

            // issue next-B global loads (latency hidden under MFMAs)
            int4 br0 = {0, 0, 0, 0}, br1 = {0, 0, 0, 0};
            if (hasNext) {
                {
                    int c = t;
                    if (c < NCB) {
                        int n = c >> 2, kc = c & 3;
                        int ch = nks * 32 + kc * 8;
                        if (ch < CHS_IN)
                            br0 = *(const int4*)(Bw + (size_t)((i * NT + ntap) * COUT + n) * CHS_IN + ch);
                    }
                }
                if constexpr (NCB > 512) {
                    int c2 = t + 512;
                    int n = c2 >> 2, kc = c2 & 3;
                    int ch = nks * 32 + kc * 8;
                    if (ch < CHS_IN)
                        br1 = *(const int4*)(Bw + (size_t)((i * NT + ntap) * COUT + n) * CHS_IN + ch);
            }
            }

            // compute this tap
            const int kh = tap / KS, kw = tap - kh * KS;
            const int toff = kh * TC + kw;
            const short* Bt = Btile + buf * (COUT * 32);

            bf16x8 af[4];
            #pragma unroll
            for (int fm = 0; fm < 4; ++fm) {
                int p = pb[fm] + toff;
                af[fm] = *(const bf16x8*)(Atile + p * 32 + ((kb ^ (p & 3)) << 3));
            }
            bf16x8 bfr[NFN];
            #pragma unroll
            for (int fn = 0; fn < NFN; ++fn)
                bfr[fn] = *(const bf16x8*)(Bt + boff[fn]);
            #pragma unroll
            for (int fm = 0; fm < 4; ++fm)
                #pragma unroll
                for (int fn = 0; fn < NFN; ++fn)
                    acc[fm][fn] = __builtin_amdgcn_mfma_f32_16x16x32_bf16(af[fm], bfr[fn], acc[fm][fn], 0, 0, 0);

            // write next B into the other buffer
            if (hasNext) {
                short* Bn = Btile + (buf ^ 1) * (COUT * 32);
                {
                    int c = t;
                    if (c < NCB) {
                        int n = c >> 2, kc = c & 3;
                        *(int4*)(Bn + n * 32 + ((kc ^ (n & 3)) << 3)) = br0;
                    }
                }
                if constexpr (NCB > 512) {
                    int c2 = t + 512;
                    int n = c2 >> 2, kc = c2 & 3;
                    *(int4*)(Bn + n * 32 + ((kc ^ (n & 3)) << 3)) = br1;
                }
            }
            __syncthreads();
            if (lastTap && ks + 1 < NKS) {
                stageA(ks + 1);
                __syncthreads();
            }
            buf ^= 1;
        }
    }

    // ---------------- epilogue: bias + relu + store + DCT reduction ----------------
    float cwv[2][4];
    #pragma unroll
    for (int par = 0; par < 2; ++par)
        #pragma unroll
        for (int r = 0; r < 4; ++r)
            cwv[par][r] = cosf(PI_F * (par * 16 + kb * 4 + r + 0.5f) / 32.f);

    #pragma unroll
    for (int fn = 0; fn < NFN; ++fn) {
        int n = wn * (COUT / 2) + fn * 16 + lm;
        float bv = bias[i * COUT + n];
        float s0 = 0.f, s1 = 0.f;
        #pragma unroll
        for (int fm = 0; fm < 4; ++fm) {
            int imgrow = wm * 2 + (fm >> 1);
            int par = fm & 1;
            #pragma unroll
            for (int r = 0; r < 4; ++r) {
                float v = fmaxf(acc[fm][fn][r] + bv, 0.f);
                if constexpr (CHS_OUT > 0) {
                    int col = par * 16 + kb * 4 + r;
                    int R = r0 + imgrow;
                    sOut[(size_t)(pairPx + R * 32 + col) * CHS_OUT + n] = f2bf(v);
                }
                s0 += v;
                s1 += v * cwv[par][r];
            }
        }
        s0 += __shfl_xor(s0, 16); s1 += __shfl_xor(s1, 16);
        s0 += __shfl_xor(s0, 32); s1 += __shfl_xor(s1, 32);
        if (kb == 0) {
            int ch = i * 448 + FOFF + n;
            atomicAdd(&sums[((size_t)b * 3584 + ch) * 2 + 0], s0);
            atomicAdd(&sums[((size_t)b * 3584 + ch) * 2 + 1], s1);
        }
    }
}

// ---------------- head: LN stats (16 blocks) + parallel GEMV (960 blocks) ----------------
__global__ __launch_bounds__(256) void ln_stats(const float* __restrict__ sums,
                                                float* __restrict__ stats) {
    __shared__ float red[8];
    const int b = blockIdx.x;
    const int t = threadIdx.x, lane = t & 63, wv = t >> 6;
    const float* S = sums + (size_t)b * 7168;
    float ls = 0.f, lq = 0.f;
    for (int f = t; f < 7168; f += 256) { float v = S[f]; ls += v; lq += v * v; }
    for (int m = 1; m < 64; m <<= 1) { ls += __shfl_xor(ls, m); lq += __shfl_xor(lq, m); }
    if (lane == 0) { red[wv] = ls; red[4 + wv] = lq; }
    __syncthreads();
    if (t == 0) {
        float ts = red[0] + red[1] + red[2] + red[3];
        float tq = red[4] + red[5] + red[6] + red[7];
        float mu  = ts * (1.f / 7168.f);
        float var = tq * (1.f / 7168.f) - mu * mu;
        stats[b * 2 + 0] = mu;
        stats[b * 2 + 1] = rsqrtf(var + 1e-5f);
    }
}

// one block per (image b, class n): both dot products + block reduce
__global__ __launch_bounds__(256) void head_gemv(
    const float* __restrict__ sums,   // [16][7168]
    const float* __restrict__ stats,  // [16][2]
    const float* __restrict__ Wg, const float* __restrict__ bg,
    const float* __restrict__ gamma, const float* __restrict__ beta,
    const float* __restrict__ Wd, const float* __restrict__ bd,
    float* __restrict__ out)          // [960 gap][960 dct]
{
    __shared__ float red[8];
    const int n = blockIdx.x % 60;
    const int b = blockIdx.x / 60;
    const int t = threadIdx.x, lane = t & 63, wv = t >> 6;
    const float* S  = sums + (size_t)b * 7168;
    const float mu  = stats[b * 2 + 0];
    const float inv = stats[b * 2 + 1];

    const float* wd = Wd + (size_t)n * 7168;
    float accd = 0.f;
    for (int f = t; f < 7168; f += 256) {
        float v = (S[f] - mu) * inv * gamma[f] + beta[f];
        accd = fmaf(v, wd[f], accd);
    }
    const float* wg = Wg + (size_t)n * 3584;
    float accg = 0.f;
    for (int ch = t; ch < 3584; ch += 256)
        accg = fmaf(S[2 * ch], wg[ch], accg);

    for (int m = 1; m < 64; m <<= 1) { accg += __shfl_xor(accg, m); accd += __shfl_xor(accd, m); }
    if (lane == 0) { red[wv] = accg; red[4 + wv] = accd; }
    __syncthreads();
    if (t == 0) {
        float g = red[0] + red[1] + red[2] + red[3];
        float d = red[4] + red[5] + red[6] + red[7];
        out[b * 60 + n]       = g * (1.f / 1024.f) + bg[n];
        out[960 + b * 60 + n] = d + bd[n];
    }
}

extern "C" void kernel_launch(void* const* d_in, const int* in_sizes, int n_in,
                              void* d_out, int out_size, void* d_ws, size_t ws_size,
                              hipStream_t stream)
{
    const float* x     = (const float*)d_in[0];
    const float* w3    = (const float*)d_in[1];
    const float* b3    = (const float*)d_in[2];
    const float* w5    = (const float*)d_in[3];
    const float* b5    = (const float*)d_in[4];
    const float* w7    = (const float*)d_in[5];
    const float* b7    = (const float*)d_in[6];
    const float* Wg    = (const float*)d_in[7];
    const float* bg    = (const float*)d_in[8];
    const float* gamma = (const float*)d_in[9];
    const float* beta  = (const float*)d_in[10];
    const float* Wd    = (const float*)d_in[11];
    const float* bd    = (const float*)d_in[12];
    float* out = (float*)d_out;

    // workspace layout (bytes)
    char* p = (char*)d_ws;
    float* sums  = (float*)p;             p += 458752;      // 16*3584*2 f32
    float* stats = (float*)p;             p += 128;         // 16*2 f32
    short* s1in = (short*)p;              p += 4194304;     // [16][4][1024][32] bf16
    short* s2in = (short*)p;              p += 18874368;    // [128][1024][72]  bf16
    short* s3in = (short*)p;              p += 35651584;    // [128][1024][136] bf16
    short* Bw3  = (short*)p;              p += 294912;      // [8][9][64][32]
    short* Bw5  = (short*)p;              p += 3686400;     // [8][25][128][72]
    short* Bw7  = (short*)p;              p += 27262976;    // [8][49][256][136]

    hipMemsetAsync(sums, 0, 458752, stream);
    prep_s1in<<<dim3(1024), dim3(256), 0, stream>>>(x, s1in);
    prep_sx<<<dim3(512), dim3(256), 0, stream>>>(x, s2in, 72, 64);
    prep_sx<<<dim3(512), dim3(256), 0, stream>>>(x, s3in, 136, 128);
    wprep<<<dim3((18432 + 255) / 256), dim3(256), 0, stream>>>(w3, Bw3, 9, 64, 4, 32, 18432);
    wprep<<<dim3((230400 + 255) / 256), dim3(256), 0, stream>>>(w5, Bw5, 25, 128, 68, 72, 230400);
    wprep<<<dim3((1705984 + 255) / 256), dim3(256), 0, stream>>>(w7, Bw7, 49, 256, 132, 136, 1705984);

    conv_mfma<3, 1, 64, 32, 72, 0, true><<<dim3(512), dim3(512), 0, stream>>>(s1in, s2in, Bw3, b3, sums);
    conv_mfma<5, 3, 128, 72, 136, 64, false><<<dim3(512), dim3(512), 0, stream>>>(s2in, s3in, Bw5, b5, sums);
    conv_mfma<7, 5, 256, 136, 0, 192, false><<<dim3(512), dim3(512), 0, stream>>>(s3in, nullptr, Bw7, b7, sums);

    ln_stats<<<dim3(16), dim3(256), 0, stream>>>(sums, stats);
    head_gemv<<<dim3(960), dim3(256), 0, stream>>>(sums, stats, Wg, bg, gamma, beta, Wd, bd, out);
}

// Round 4
// 580.276 us; speedup vs baseline: 14.1903x; 1.2432x over previous
//
#include <hip/hip_runtime.h>
#include <math.h>

#define PI_F 3.14159265358979323846f

typedef short bf16x8 __attribute__((ext_vector_type(8)));
typedef float f32x4  __attribute__((ext_vector_type(4)));

__device__ __forceinline__ short f2bf(float f) {
    union { float f; unsigned u; } v; v.f = f;
    unsigned r = v.u + 0x7fffu + ((v.u >> 16) & 1u);
    return (short)(r >> 16);
}

// ---------------- prep kernels ----------------

// s1in: [b][g][1024][8] bf16: ch 0..3 = x group, 4..7 = 0
__global__ __launch_bounds__(256) void prep_s1in(const float* __restrict__ x, short* __restrict__ dst) {
    int idx = blockIdx.x * 256 + threadIdx.x;
    if (idx >= 64 * 1024) return;
    int px = idx & 1023;
    int g  = (idx >> 10) & 3;
    int b  = idx >> 12;
    short v8[8];
    #pragma unroll
    for (int j = 0; j < 8; ++j) {
        float f = (j < 4) ? x[((b * 16 + g * 4 + j) << 10) + px] : 0.f;
        v8[j] = f2bf(f);
    }
    *(int4*)(dst + (size_t)idx * 8) = *(const int4*)v8;
}

// write x-group (4 ch) + 4 zeros at channel CH0 of a [pair][1024][CHS] bf16 buffer
__global__ __launch_bounds__(256) void prep_sx(const float* __restrict__ x, short* __restrict__ dst,
                                               int CHS, int CH0) {
    int idx = blockIdx.x * 256 + threadIdx.x;          // (pair, px)
    if (idx >= 128 * 1024) return;
    int px = idx & 1023, pair = idx >> 10;
    int i = pair >> 4, b = pair & 15, g = i >> 1;
    short v8[8];
    #pragma unroll
    for (int j = 0; j < 8; ++j) {
        float f = (j < 4) ? x[((b * 16 + g * 4 + j) << 10) + px] : 0.f;
        v8[j] = f2bf(f);
    }
    *(int4*)(dst + (size_t)idx * CHS + CH0) = *(const int4*)v8;
}

// weights [8][COUT][CINR][KS*KS] fp32 -> dense-K layout [8][kh][chunk][COUT][32] bf16
// within a kh: k = kwc*CHS + ch  (zeros for ch>=CINR or kwc>=KS)
template<int KS, int CHS, int CINR, int COUT, int NCH>
__global__ __launch_bounds__(256) void wprep_d(const float* __restrict__ w, short* __restrict__ Bw) {
    constexpr int TOTAL = 8 * KS * NCH * COUT * 4;
    int idx = blockIdx.x * 256 + threadIdx.x;
    if (idx >= TOTAL) return;
    int kb = idx & 3;
    int r  = idx >> 2;
    int n  = r % COUT;  r /= COUT;
    int c  = r % NCH;   r /= NCH;
    int kh = r % KS;
    int br = r / KS;
    short v8[8];
    #pragma unroll
    for (int j = 0; j < 8; ++j) {
        int k   = c * 32 + kb * 8 + j;
        int kwc = k / CHS;
        int ch  = k - kwc * CHS;
        float f = (kwc < KS && ch < CINR)
                ? w[(((size_t)br * COUT + n) * CINR + ch) * (KS * KS) + kh * KS + kwc] : 0.f;
        v8[j] = f2bf(f);
    }
    *(int4*)(Bw + (size_t)idx * 8) = *(const int4*)v8;
}

// ---------------- MFMA conv stage (dense-K, B from global) ----------------
// 512 thr = 8 waves (WM x WN), per-wave 64x64 output tile (4x4 16x16 frags; NFN may be 2).
// A: [ROWS][TCX][CHS] bf16 in LDS, restaged per kh (2 barriers per kh, none per chunk).
// B: loaded per-chunk straight from global (L1/L2-resident panel, frag-layout prepped).
template<int KS, int CHS, int COUT, int CHS_OUT, int FOFF, bool S1SRC, int WN>
__global__ __launch_bounds__(512, 4) void conv_mfma(
    const short* __restrict__ sIn,
    short* __restrict__ sOut,
    const short* __restrict__ Bw,      // [8][KS][NCH][COUT][32] bf16
    const float* __restrict__ bias,    // [8][COUT]
    float* __restrict__ sums)          // [16][3584][2] fp32
{
    constexpr int PAD  = KS / 2;
    constexpr int NCH  = (KS * CHS + 31) / 32;          // K-chunks per kh-row
    constexpr int TCX  = 32 + (NCH * 32 - 1) / CHS;     // staged cols (incl. overread)
    constexpr int WM   = 8 / WN;
    constexpr int ROWS = 2 * WM;                        // image rows per block
    constexpr int NFN  = COUT / (16 * WN);
    constexpr int CPP  = CHS / 8;                       // 16B chunks per pixel
    constexpr int TCHK = ROWS * TCX * CPP;              // 16B chunks in A tile

    __shared__ short Atile[ROWS * TCX * CHS];

    const int t    = threadIdx.x;
    const int lane = t & 63, w = t >> 6;
    const int wm = w / WN, wn = w % WN;
    const int lm = lane & 15, kb = lane >> 4;

    const int bid = blockIdx.x;
    const int i  = bid & 7;            // branch (-> XCD locality for B stream)
    const int b  = (bid >> 3) & 15;    // image
    const int mt = bid >> 7;           // m-tile
    const int r0 = mt * ROWS;

    const int pairPx = (i * 16 + b) << 10;
    const int srcPx  = S1SRC ? ((b * 4 + (i >> 1)) << 10) : pairPx;

    // A-frag bases (shorts): (tr*TCX + C)*CHS + kb*8 ; per chunk add 32
    int aBase[4];
    #pragma unroll
    for (int fm = 0; fm < 4; ++fm) {
        int tr = wm * 2 + (fm >> 1);
        int C  = (fm & 1) * 16 + lm;
        aBase[fm] = (tr * TCX + C) * CHS + kb * 8;
    }
    // B-frag offsets within a chunk panel (shorts): n*32 + kb*8
    int nIdx[NFN], nOff[NFN];
    #pragma unroll
    for (int fn = 0; fn < NFN; ++fn) {
        nIdx[fn] = wn * (COUT / WN) + fn * 16 + lm;
        nOff[fn] = nIdx[fn] * 32 + kb * 8;
    }

    f32x4 acc[4][NFN];
    #pragma unroll
    for (int fm = 0; fm < 4; ++fm)
        #pragma unroll
        for (int fn = 0; fn < NFN; ++fn)
            acc[fm][fn] = (f32x4){0.f, 0.f, 0.f, 0.f};

    const short* BwI = Bw + (size_t)i * KS * NCH * COUT * 32;

    for (int kh = 0; kh < KS; ++kh) {
        __syncthreads();
        // stage A rows for this kh: tile[tr][tc][ch] = in[r0+kh-PAD+tr][tc-PAD][ch]
        for (int e = t; e < TCHK; e += 512) {
            int kc = e % CPP, r = e / CPP;
            int tc = r % TCX, tr = r / TCX;
            int rin = r0 + kh - PAD + tr, cin = tc - PAD;
            int4 v = {0, 0, 0, 0};
            if (rin >= 0 && rin < 32 && cin >= 0 && cin < 32)
                v = *(const int4*)(sIn + (size_t)(srcPx + rin * 32 + cin) * CHS + kc * 8);
            *(int4*)(Atile + (size_t)e * 8) = v;
        }
        __syncthreads();

        const short* Bp = BwI + (size_t)kh * NCH * COUT * 32;
        #pragma unroll 2
        for (int c = 0; c < NCH; ++c) {
            bf16x8 bfr[NFN], af[4];
            #pragma unroll
            for (int fn = 0; fn < NFN; ++fn)
                bfr[fn] = *(const bf16x8*)(Bp + nOff[fn]);
            #pragma unroll
            for (int fm = 0; fm < 4; ++fm)
                af[fm] = *(const bf16x8*)(Atile + aBase[fm] + c * 32);
            Bp += COUT * 32;
            #pragma unroll
            for (int fm = 0; fm < 4; ++fm)
                #pragma unroll
                for (int fn = 0; fn < NFN; ++fn)
                    acc[fm][fn] = __builtin_amdgcn_mfma_f32_16x16x32_bf16(af[fm], bfr[fn], acc[fm][fn], 0, 0, 0);
        }
    }

    // ---------------- epilogue: bias + relu + store + DCT reduction ----------------
    float cwv[2][4];
    #pragma unroll
    for (int par = 0; par < 2; ++par)
        #pragma unroll
        for (int r = 0; r < 4; ++r)
            cwv[par][r] = cosf(PI_F * (par * 16 + kb * 4 + r + 0.5f) / 32.f);

    #pragma unroll
    for (int fn = 0; fn < NFN; ++fn) {
        int n = nIdx[fn];
        float bv = bias[i * COUT + n];
        float s0 = 0.f, s1 = 0.f;
        #pragma unroll
        for (int fm = 0; fm < 4; ++fm) {
            int imgrow = wm * 2 + (fm >> 1);
            int par = fm & 1;
            #pragma unroll
            for (int r = 0; r < 4; ++r) {
                float v = fmaxf(acc[fm][fn][r] + bv, 0.f);
                if constexpr (CHS_OUT > 0) {
                    int col = par * 16 + kb * 4 + r;
                    int R = r0 + imgrow;
                    sOut[(size_t)(pairPx + R * 32 + col) * CHS_OUT + n] = f2bf(v);
                }
                s0 += v;
                s1 += v * cwv[par][r];
            }
        }
        s0 += __shfl_xor(s0, 16); s1 += __shfl_xor(s1, 16);
        s0 += __shfl_xor(s0, 32); s1 += __shfl_xor(s1, 32);
        if (kb == 0) {
            int ch = i * 448 + FOFF + n;
            atomicAdd(&sums[((size_t)b * 3584 + ch) * 2 + 0], s0);
            atomicAdd(&sums[((size_t)b * 3584 + ch) * 2 + 1], s1);
        }
    }
}

// ---------------- head: LN stats (16 blocks) + parallel GEMV (960 blocks) ----------------
__global__ __launch_bounds__(256) void ln_stats(const float* __restrict__ sums,
                                                float* __restrict__ stats) {
    __shared__ float red[8];
    const int b = blockIdx.x;
    const int t = threadIdx.x, lane = t & 63, wv = t >> 6;
    const float* S = sums + (size_t)b * 7168;
    float ls = 0.f, lq = 0.f;
    for (int f = t; f < 7168; f += 256) { float v = S[f]; ls += v; lq += v * v; }
    for (int m = 1; m < 64; m <<= 1) { ls += __shfl_xor(ls, m); lq += __shfl_xor(lq, m); }
    if (lane == 0) { red[wv] = ls; red[4 + wv] = lq; }
    __syncthreads();
    if (t == 0) {
        float ts = red[0] + red[1] + red[2] + red[3];
        float tq = red[4] + red[5] + red[6] + red[7];
        float mu  = ts * (1.f / 7168.f);
        float var = tq * (1.f / 7168.f) - mu * mu;
        stats[b * 2 + 0] = mu;
        stats[b * 2 + 1] = rsqrtf(var + 1e-5f);
    }
}

__global__ __launch_bounds__(256) void head_gemv(
    const float* __restrict__ sums,   // [16][7168]
    const float* __restrict__ stats,  // [16][2]
    const float* __restrict__ Wg, const float* __restrict__ bg,
    const float* __restrict__ gamma, const float* __restrict__ beta,
    const float* __restrict__ Wd, const float* __restrict__ bd,
    float* __restrict__ out)          // [960 gap][960 dct]
{
    __shared__ float red[8];
    const int n = blockIdx.x % 60;
    const int b = blockIdx.x / 60;
    const int t = threadIdx.x, lane = t & 63, wv = t >> 6;
    const float* S  = sums + (size_t)b * 7168;
    const float mu  = stats[b * 2 + 0];
    const float inv = stats[b * 2 + 1];

    const float* wd = Wd + (size_t)n * 7168;
    float accd = 0.f;
    for (int f = t; f < 7168; f += 256) {
        float v = (S[f] - mu) * inv * gamma[f] + beta[f];
        accd = fmaf(v, wd[f], accd);
    }
    const float* wg = Wg + (size_t)n * 3584;
    float accg = 0.f;
    for (int ch = t; ch < 3584; ch += 256)
        accg = fmaf(S[2 * ch], wg[ch], accg);

    for (int m = 1; m < 64; m <<= 1) { accg += __shfl_xor(accg, m); accd += __shfl_xor(accd, m); }
    if (lane == 0) { red[wv] = accg; red[4 + wv] = accd; }
    __syncthreads();
    if (t == 0) {
        float g = red[0] + red[1] + red[2] + red[3];
        float d = red[4] + red[5] + red[6] + red[7];
        out[b * 60 + n]       = g * (1.f / 1024.f) + bg[n];
        out[960 + b * 60 + n] = d + bd[n];
    }
}

extern "C" void kernel_launch(void* const* d_in, const int* in_sizes, int n_in,
                              void* d_out, int out_size, void* d_ws, size_t ws_size,
                              hipStream_t stream)
{
    const float* x     = (const float*)d_in[0];
    const float* w3    = (const float*)d_in[1];
    const float* b3    = (const float*)d_in[2];
    const float* w5    = (const float*)d_in[3];
    const float* b5    = (const float*)d_in[4];
    const float* w7    = (const float*)d_in[5];
    const float* b7    = (const float*)d_in[6];
    const float* Wg    = (const float*)d_in[7];
    const float* bg    = (const float*)d_in[8];
    const float* gamma = (const float*)d_in[9];
    const float* beta  = (const float*)d_in[10];
    const float* Wd    = (const float*)d_in[11];
    const float* bd    = (const float*)d_in[12];
    float* out = (float*)d_out;

    // workspace layout (bytes)
    char* p = (char*)d_ws;
    float* sums  = (float*)p;             p += 458752;      // 16*3584*2 f32
    float* stats = (float*)p;             p += 128;         // 16*2 f32
    short* s1in = (short*)p;              p += 1048576;     // [64][1024][8]    bf16
    short* s2in = (short*)p;              p += 18874368;    // [128][1024][72]  bf16
    short* s3in = (short*)p;              p += 35651584;    // [128][1024][136] bf16
    short* Bw3  = (short*)p;              p += 98304;       // [8][3][1][64][32]
    short* Bw5  = (short*)p;              p += 3932160;     // [8][5][12][128][32]
    short* Bw7  = (short*)p;              p += 27525120;    // [8][7][30][256][32]

    hipMemsetAsync(sums, 0, 458752, stream);
    prep_s1in<<<dim3(256), dim3(256), 0, stream>>>(x, s1in);
    prep_sx<<<dim3(512), dim3(256), 0, stream>>>(x, s2in, 72, 64);
    prep_sx<<<dim3(512), dim3(256), 0, stream>>>(x, s3in, 136, 128);
    wprep_d<3, 8, 4, 64, 1><<<dim3(24), dim3(256), 0, stream>>>(w3, Bw3);
    wprep_d<5, 72, 68, 128, 12><<<dim3(960), dim3(256), 0, stream>>>(w5, Bw5);
    wprep_d<7, 136, 132, 256, 30><<<dim3(6720), dim3(256), 0, stream>>>(w7, Bw7);

    conv_mfma<3, 8, 64, 72, 0, true, 2><<<dim3(512), dim3(512), 0, stream>>>(s1in, s2in, Bw3, b3, sums);
    conv_mfma<5, 72, 128, 136, 64, false, 2><<<dim3(512), dim3(512), 0, stream>>>(s2in, s3in, Bw5, b5, sums);
    conv_mfma<7, 136, 256, 0, 192, false, 4><<<dim3(1024), dim3(512), 0, stream>>>(s3in, nullptr, Bw7, b7, sums);

    ln_stats<<<dim3(16), dim3(256), 0, stream>>>(sums, stats);
    head_gemv<<<dim3(960), dim3(256), 0, stream>>>(sums, stats, Wg, bg, gamma, beta, Wd, bd, out);
}